// Round 5
// baseline (18.705 us; speedup 1.0000x reference)
//
#include <hip/hip_runtime.h>
#include <hip/hip_bf16.h>

// Heatmap = per-batch GEMM  out[b] (128x128) = GY(128xK) @ GX(Kx128), K=98->128.
// Two-kernel pipeline (round-5):
//   K1: materialize bf16 factor tables in d_ws (4M exps total, 16/lane):
//       gyA[b][h][k] = exp(-(h-y_k)^2 c)   (A operand, row-major in k)
//       gxB[b][w][k] = exp(-(w-x_k)^2 c)   (B^T layout: value = B[k][w])
//       k in [98,128) padded with sentinel -1000 -> exp underflows to exact 0.
//   K2: per-batch MFMA GEMM consuming contiguous 16 B fragments directly from
//       global (L2-hot panels), layouts identical to verified round-4 kernel:
//       A: lane l holds A[l&15][(l>>4)*8+j]; B: lane holds B[(l>>4)*8+j][l&15];
//       C/D: col=l&15, row=(l>>4)*4+r.
// Dtypes (established rounds 0-3): input f32, output f32. d_ws >> 8 MB needed.

#define NB 128
#define NL 98
#define NW 128
#define NH 128
#define NK 128
#define SIGMA 5.0f

typedef __attribute__((ext_vector_type(8))) short short8;
typedef __attribute__((ext_vector_type(4))) float f32x4;

__global__ __launch_bounds__(256, 4)
void k1_tables(const float* __restrict__ X,
               __hip_bfloat16* __restrict__ gyA,
               __hip_bfloat16* __restrict__ gxB) {
    const int b    = blockIdx.x >> 3;         // batch
    const int part = blockIdx.x & 7;          // 16-row slab
    const int tid  = threadIdx.x;
    const int r    = part * 16 + (tid >> 4);  // h (for gy) and w (for gx)
    const int k0   = (tid & 15) * 8;          // k-octet
    const float c  = 1.0f / (2.0f * SIGMA * SIGMA);
    const float* Xb = X + (size_t)b * 2 * NL; // 8B-aligned (784*b)

    float xv[8], yv[8];
    #pragma unroll
    for (int j = 0; j < 8; ++j) {
        int k  = k0 + j;
        int kc = k < NL ? k : NL - 1;                       // clamp addr in-bounds
        float2 p = *reinterpret_cast<const float2*>(Xb + 2 * kc);
        bool valid = k < NL;
        xv[j] = valid ? p.x : -1000.0f;                     // sentinel -> exp == 0
        yv[j] = valid ? p.y : -1000.0f;
    }

    const float fr = (float)r;
    __hip_bfloat16 gy[8], gx[8];
    #pragma unroll
    for (int j = 0; j < 8; ++j) {
        float dy = fr - yv[j];
        float dx = fr - xv[j];
        gy[j] = __float2bfloat16(__expf(-dy * dy * c));
        gx[j] = __float2bfloat16(__expf(-dx * dx * c));
    }

    // 16 B stores, coalesced across the 16 k-octet lanes of each row
    size_t base = ((size_t)b * NH + r) * NK + k0;
    *reinterpret_cast<short8*>(gyA + base) = *reinterpret_cast<const short8*>(gy);
    *reinterpret_cast<short8*>(gxB + base) = *reinterpret_cast<const short8*>(gx);
}

__global__ __launch_bounds__(256, 2)
void k2_gemm(const __hip_bfloat16* __restrict__ gyA,
             const __hip_bfloat16* __restrict__ gxB,
             float* __restrict__ out) {
    const int b    = blockIdx.x >> 2;
    const int row0 = (blockIdx.x & 3) * 32;
    const int tid  = threadIdx.x;
    const int wid  = tid >> 6;
    const int lane = tid & 63;
    const int l16  = lane & 15;
    const int kg   = lane >> 4;
    const int colw = wid * 32;

    const __hip_bfloat16* Ab = gyA + (size_t)b * NH * NK;
    const __hip_bfloat16* Bb = gxB + (size_t)b * NW * NK;

    f32x4 acc[2][2] = {};
    #pragma unroll
    for (int ks = 0; ks < 4; ++ks) {
        const int k0 = ks * 32 + kg * 8;
        short8 af[2], bf[2];
        af[0] = *reinterpret_cast<const short8*>(Ab + (row0      + l16) * NK + k0);
        af[1] = *reinterpret_cast<const short8*>(Ab + (row0 + 16 + l16) * NK + k0);
        bf[0] = *reinterpret_cast<const short8*>(Bb + (colw      + l16) * NK + k0);
        bf[1] = *reinterpret_cast<const short8*>(Bb + (colw + 16 + l16) * NK + k0);
        #pragma unroll
        for (int m = 0; m < 2; ++m)
            #pragma unroll
            for (int n = 0; n < 2; ++n)
                acc[m][n] = __builtin_amdgcn_mfma_f32_16x16x32_bf16(
                    af[m], bf[n], acc[m][n], 0, 0, 0);
    }

    #pragma unroll
    for (int m = 0; m < 2; ++m)
        #pragma unroll
        for (int n = 0; n < 2; ++n)
            #pragma unroll
            for (int r = 0; r < 4; ++r) {
                int row = row0 + m * 16 + kg * 4 + r;
                int col = colw + n * 16 + l16;
                out[((size_t)b * NH + row) * NW + col] = acc[m][n][r];
            }
}

extern "C" void kernel_launch(void* const* d_in, const int* in_sizes, int n_in,
                              void* d_out, int out_size, void* d_ws, size_t ws_size,
                              hipStream_t stream) {
    const float* X = (const float*)d_in[0];
    float* out = (float*)d_out;
    __hip_bfloat16* gyA = (__hip_bfloat16*)d_ws;
    __hip_bfloat16* gxB = gyA + (size_t)NB * NH * NK;   // +4 MB

    k1_tables<<<dim3(NB * 8), dim3(256), 0, stream>>>(X, gyA, gxB);
    k2_gemm  <<<dim3(NB * 4), dim3(256), 0, stream>>>(gyA, gxB, out);
}

// Round 6
// 10.588 us; speedup vs baseline: 1.7666x; 1.7666x over previous
//
#include <hip/hip_runtime.h>
#include <hip/hip_bf16.h>

// Heatmap = per-batch GEMM out[b](128x128) = GY(128xK) @ GX(Kx128), K=98->128
// (pad k in [98,128) with sentinel coord -1000 -> exp2 underflows to exact 0).
//
// Round-6 (post r5 lesson: multi-dispatch loses; single kernel only):
//  - grid 1024 = 128 batches x 8 sixteen-row tiles, 256 thr -> 4 blocks/CU,
//    4 waves/SIMD (2x round-4 occupancy).
//  - gy panel (16 rows x 128 k, bf16) computed ONCE per block into XOR-swizzled
//    LDS (byte ^= (row&7)<<4; without swizzle the A-frag ds_read_b128 at
//    row-stride 256 B is a 16-way bank conflict). gx computed reg-direct.
//    72 exps/lane vs round-4's 128.
//  - coords pre-scaled by S = sqrt(c*log2e) so factor = exp2(-(d')^2):
//    sub + neg-mul + v_exp per Gaussian.
// MFMA 16x16x32 bf16 layouts (verified r4): A: lane holds A[l&15][(l>>4)*8+j];
// B: lane holds B[(l>>4)*8+j][l&15]; C/D: col=l&15, row=(l>>4)*4+r.
// Dtypes (rounds 0-3): input f32, output f32.

#define NB 128
#define NL 98
#define NW 128
#define NH 128
#define SIGMA 5.0f

// S = sqrt( 1/(2*sigma^2) * log2(e) ) = sqrt(0.02 * 1.44269504)
#define SCALE 0.16986437f

#if __has_builtin(__builtin_amdgcn_exp2f)
#define EXP2(x) __builtin_amdgcn_exp2f(x)
#else
#define EXP2(x) exp2f(x)
#endif

typedef __attribute__((ext_vector_type(8))) short short8;
typedef __attribute__((ext_vector_type(4))) float f32x4;

__global__ __launch_bounds__(256, 4)
void heatmap_v6(const float* __restrict__ X, float* __restrict__ out) {
    const int b    = blockIdx.x >> 3;
    const int row0 = (blockIdx.x & 7) * 16;
    const int tid  = threadIdx.x;
    const int wid  = tid >> 6;
    const int lane = tid & 63;
    const int l16  = lane & 15;
    const int kg   = lane >> 4;
    const int colw = wid * 32;

    __shared__ float lmS[256];       // scaled coords, sentinel-padded
    __shared__ short gyT[16 * 128];  // swizzled bf16 gy panel (4 KB)

    if (tid < 2 * NL) lmS[tid] = X[(size_t)b * 2 * NL + tid] * SCALE;
    else              lmS[tid] = -1000.0f;   // scaled-space sentinel -> exp2 == 0
    __syncthreads();

    // Fill gy panel: thread -> (row = tid>>4, k-octet = tid&15), 8 exps.
    {
        const int row = tid >> 4;
        const int oct = tid & 15;
        const float fr = (float)(row0 + row) * SCALE;
        __hip_bfloat16 g[8];
        #pragma unroll
        for (int j = 0; j < 8; ++j) {
            float d = fr - lmS[2 * (oct * 8 + j) + 1];
            g[j] = __float2bfloat16(EXP2(-d * d));
        }
        const int byte = row * 256 + ((oct * 16) ^ ((row & 7) << 4));
        *reinterpret_cast<short8*>(reinterpret_cast<char*>(gyT) + byte) =
            *reinterpret_cast<const short8*>(g);
    }
    __syncthreads();

    const float2* lm2 = (const float2*)lmS;             // lm2[k] = (xS, yS)
    const float colS0 = (float)(colw + l16) * SCALE;
    const float colS1 = (float)(colw + 16 + l16) * SCALE;

    f32x4 acc[2] = {};
    #pragma unroll
    for (int ks = 0; ks < 4; ++ks) {
        const int k0 = ks * 32 + kg * 8;
        // A-frag: gy row l16, k in [k0, k0+8) from swizzled LDS (16 B read)
        const int abyte = l16 * 256 + ((ks * 64 + kg * 16) ^ ((l16 & 7) << 4));
        short8 af = *reinterpret_cast<const short8*>(
            reinterpret_cast<const char*>(gyT) + abyte);

        // B-frags: gx for this lane's two cols, computed in-register
        short8 bf0, bf1;
        #pragma unroll
        for (int j = 0; j < 8; ++j) {
            float xs = lm2[k0 + j].x;                   // broadcast LDS read
            float d0 = colS0 - xs;
            float d1 = colS1 - xs;
            __hip_bfloat16 h0 = __float2bfloat16(EXP2(-d0 * d0));
            __hip_bfloat16 h1 = __float2bfloat16(EXP2(-d1 * d1));
            bf0[j] = *reinterpret_cast<const short*>(&h0);
            bf1[j] = *reinterpret_cast<const short*>(&h1);
        }

        acc[0] = __builtin_amdgcn_mfma_f32_16x16x32_bf16(af, bf0, acc[0], 0, 0, 0);
        acc[1] = __builtin_amdgcn_mfma_f32_16x16x32_bf16(af, bf1, acc[1], 0, 0, 0);
    }

    // Epilogue: C/D col=l16, row=kg*4+r within each 16x16 tile.
    #pragma unroll
    for (int n = 0; n < 2; ++n)
        #pragma unroll
        for (int r = 0; r < 4; ++r) {
            int row = row0 + kg * 4 + r;
            int col = colw + n * 16 + l16;
            out[((size_t)b * NH + row) * NW + col] = acc[n][r];
        }
}

extern "C" void kernel_launch(void* const* d_in, const int* in_sizes, int n_in,
                              void* d_out, int out_size, void* d_ws, size_t ws_size,
                              hipStream_t stream) {
    const float* X = (const float*)d_in[0];
    float* out = (float*)d_out;
    heatmap_v6<<<dim3(NB * 8), dim3(256), 0, stream>>>(X, out);
}